// Round 15
// baseline (79.131 us; speedup 1.0000x reference)
//
#include <hip/hip_runtime.h>
#include <hip/hip_bf16.h>
#include <math.h>

#define NPIX 9216
#define NBLK 32          // k1 blocks per batch (grid 512 = 2/CU exactly)
#define NTILE 288        // 32-px tiles per batch (k3 / qbf granularity)
#define SCALE 0.17677669529663687f   // 32^-0.5
#define SQRT128 11.313708498984761f

typedef __attribute__((ext_vector_type(8))) short short8;
typedef __attribute__((ext_vector_type(4))) float f32x4;

static __device__ __forceinline__ unsigned short f2bf(float f) {
  return __bfloat16_as_ushort(__float2bfloat16(f));
}
static __device__ __forceinline__ float bf2f(unsigned short h) {
  return __bfloat162float(__ushort_as_bfloat16(h));
}

// d-permutation: q's B-fragment k-slot j at lane-group lg holds channel
// d = (j>>2)*16 + lg*4 + (j&3). ctxnT's d-columns stored in the same slot
// order: col c = ((d>>2)&3)*8 + ((d>>4)&1)*4 + (d&3). A/B pair slot-to-slot.

// Primary ws layout:
//   part_ctx f32[16][NBLK][4096]
//   part_se  f32[16][NBLK][128]
//   wbf2  bf16[96 groups][64 lanes][8]   (qkv_w*norm_g, fragment order, HEAD-major)
//   owb2  bf16[32 groups][64 lanes][8]   (out_w, fragment order)
//   ctxnT bf16[16][4][32][32]            ([b][h][e][dperm], normalized)
//   qbf   bf16[16][NTILE][4][2][64][8]   (softmaxed q, B-fragment order, dperm slots)

__global__ __launch_bounds__(256) void k_prep2(
    const float* __restrict__ qkv_w, const float* __restrict__ norm_g,
    const float* __restrict__ out_w,
    unsigned short* __restrict__ wbf2, unsigned short* __restrict__ owb2) {
  const int i = blockIdx.x * 256 + threadIdx.x;
  if (i < 6144) {              // wbf2: 96 groups x 64 lanes, head-major rows
    const int g = i >> 6, lane = i & 63;
    const int wv = g / 24, rem = g % 24;   // g = (wv*6+mt)*4+ks
    const int mt = rem >> 2, ks = rem & 3;
    const int row = (mt >> 1) * 128 + wv * 32 + (mt & 1) * 16 + (lane & 15);
    const int col = ks * 32 + (lane >> 4) * 8;
    const float* src = qkv_w + row * 128 + col;
    const float* gg = norm_g + col;
    uint4 o;
    o.x = (unsigned)f2bf(src[0] * gg[0]) | ((unsigned)f2bf(src[1] * gg[1]) << 16);
    o.y = (unsigned)f2bf(src[2] * gg[2]) | ((unsigned)f2bf(src[3] * gg[3]) << 16);
    o.z = (unsigned)f2bf(src[4] * gg[4]) | ((unsigned)f2bf(src[5] * gg[5]) << 16);
    o.w = (unsigned)f2bf(src[6] * gg[6]) | ((unsigned)f2bf(src[7] * gg[7]) << 16);
    *(uint4*)(wbf2 + (size_t)i * 8) = o;
  } else if (i < 8192) {       // owb2: 32 groups x 64 lanes
    const int i2 = i - 6144;
    const int g = i2 >> 6, lane = i2 & 63;  // g = (wv*2+mt)*4+ks
    const int wv = g >> 3, rem = g & 7;
    const int mt = rem >> 2, ks = rem & 3;
    const int row = 32 * wv + mt * 16 + (lane & 15);
    const int col = ks * 32 + (lane >> 4) * 8;
    const float* src = out_w + row * 128 + col;
    uint4 o;
    o.x = (unsigned)f2bf(src[0]) | ((unsigned)f2bf(src[1]) << 16);
    o.y = (unsigned)f2bf(src[2]) | ((unsigned)f2bf(src[3]) << 16);
    o.z = (unsigned)f2bf(src[4]) | ((unsigned)f2bf(src[5]) << 16);
    o.w = (unsigned)f2bf(src[6]) | ((unsigned)f2bf(src[7]) << 16);
    *(uint4*)(owb2 + (size_t)i2 * 8) = o;
  }
}

// fallback-path ctx init from mem_kv
__global__ __launch_bounds__(256) void k_init(const float* __restrict__ mem_kv,
                                              float* __restrict__ ctxG,
                                              float* __restrict__ sumexpG) {
  const int bh = blockIdx.x;
  const int h = bh & 3;
  const float* mk = mem_kv + h * 128;
  const float* mv = mem_kv + 512 + h * 128;
  const int t = threadIdx.x;
  const int d = t >> 3, e0 = (t & 7) * 4;
  float ek[4], se = 0.f;
#pragma unroll
  for (int j = 0; j < 4; ++j) { ek[j] = __expf(mk[d * 4 + j]); se += ek[j]; }
#pragma unroll
  for (int ei = 0; ei < 4; ++ei) {
    const int e = e0 + ei;
    float s = 0.f;
#pragma unroll
    for (int j = 0; j < 4; ++j) s += ek[j] * mv[e * 4 + j];
    ctxG[(bh * 32 + d) * 32 + e] = s;
  }
  if ((t & 7) == 0) sumexpG[bh * 32 + d] = se;
}

// Fused MFMA k1, round 15: 64-PIXEL TILES (serial-spine amortization).
// Rounds 10-14 proved k1 is bound by a per-tile serial spine (~6-9k cy/tile
// vs ~1k issuable) that barriers/occupancy/LDS-ops/weight-residency don't
// shorten. This round: half the spines (4.5 tiles of 64px vs 6+3-tail of
// 32px), grid 512 = 2 blocks/CU exact (no tail), no-max softmax (|q|<~3,
// exp-safe), all-64-lane inv. kv [4][64][72] (144B row stride: b128-aligned,
// banks spread); xnT single [64][136]; redu [16][64]. LDS 58.4KB.
template <bool WSQ>
__global__ __launch_bounds__(256, 2) void k1(
    const float* __restrict__ x, const unsigned short* __restrict__ wbf2,
    unsigned short* __restrict__ qb16, float* __restrict__ qf32,
    float* __restrict__ ctx_dst, float* __restrict__ se_dst) {
  __shared__ __align__(16) unsigned char smem[36864 + 17408 + 4096];
  unsigned short* kv = (unsigned short*)smem;                   // [4][64][72]
  unsigned short* xnT = (unsigned short*)(smem + 36864);        // [64][136]
  float* redu = (float*)(smem + 36864 + 17408);                 // [16][64]

  const int t = threadIdx.x;
  const int b = blockIdx.y;
  const int blk = blockIdx.x;          // 0..31
  const int wv = t >> 6;
  const int lane = t & 63;
  const int lr = lane & 15;
  const int lg = lane >> 4;
  const int r = t >> 3, c4 = (t & 7) * 4;
  const float* xb = x + ((size_t)b * 128) * NPIX;
  unsigned short* kv_w = kv + wv * 64 * 72;   // this wave's private k/v region

  const int tstart = (blk < 16) ? blk * 5 : 80 + (blk - 16) * 4;
  const int tcnt = (blk < 16) ? 5 : 4;

  f32x4 ctx[2][2];
#pragma unroll
  for (int i = 0; i < 2; ++i)
#pragma unroll
    for (int j = 0; j < 2; ++j)
#pragma unroll
      for (int q = 0; q < 4; ++q) ctx[i][j][q] = 0.f;
  float se_row[2] = {0.f, 0.f};

  float4 pf[8];   // prefetched x tile: [pass 0..3][half 0..1]
#pragma unroll
  for (int pass = 0; pass < 4; ++pass)
#pragma unroll
    for (int hf = 0; hf < 2; ++hf)
      pf[pass * 2 + hf] = *(const float4*)(
          xb + (size_t)(pass * 32 + r) * NPIX + tstart * 64 + hf * 32 + c4);

  for (int it = 0; it < tcnt; ++it) {
    const int T = tstart + it;

    {  // phase L: regs -> bf16 transpose into xnT + paired sumsq partials
      float ss[8];
#pragma unroll
      for (int i = 0; i < 8; ++i) ss[i] = 0.f;
#pragma unroll
      for (int pass = 0; pass < 4; ++pass)
#pragma unroll
        for (int hf = 0; hf < 2; ++hf) {
          const int row = pass * 32 + r;
          const int px0 = hf * 32 + c4;
          const float4 v = pf[pass * 2 + hf];
          xnT[(px0 + 0) * 136 + row] = f2bf(v.x);
          xnT[(px0 + 1) * 136 + row] = f2bf(v.y);
          xnT[(px0 + 2) * 136 + row] = f2bf(v.z);
          xnT[(px0 + 3) * 136 + row] = f2bf(v.w);
          ss[hf * 4 + 0] = fmaf(v.x, v.x, ss[hf * 4 + 0]);
          ss[hf * 4 + 1] = fmaf(v.y, v.y, ss[hf * 4 + 1]);
          ss[hf * 4 + 2] = fmaf(v.z, v.z, ss[hf * 4 + 2]);
          ss[hf * 4 + 3] = fmaf(v.w, v.w, ss[hf * 4 + 3]);
        }
      // pair-reduce rows r and r^1 (t^8), then write redu[16][64]
#pragma unroll
      for (int i = 0; i < 8; ++i) ss[i] += __shfl_xor(ss[i], 8);
      if (!(t & 8)) {
        *(float4*)&redu[(t >> 4) * 64 + c4] =
            make_float4(ss[0], ss[1], ss[2], ss[3]);
        *(float4*)&redu[(t >> 4) * 64 + 32 + c4] =
            make_float4(ss[4], ss[5], ss[6], ss[7]);
      }
    }
    __syncthreads();  // barrier A: xnT + redu visible
    float iv[4];
    {  // all-64-lane inv: lane's px = lane; shfl-distribute to nt groups
      float s = 0.f;
#pragma unroll
      for (int g = 0; g < 16; ++g) s += redu[g * 64 + lane];
      const float invv = SQRT128 / fmaxf(sqrtf(s), 1e-12f);
#pragma unroll
      for (int nt = 0; nt < 4; ++nt) iv[nt] = __shfl(invv, nt * 16 + lr);
    }
    short8 bfr[4][4];
#pragma unroll
    for (int ks = 0; ks < 4; ++ks)
#pragma unroll
      for (int nt = 0; nt < 4; ++nt)
        bfr[ks][nt] = *(const short8*)&xnT[(nt * 16 + lr) * 136 + ks * 32 + lg * 8];
    if (it + 1 < tcnt) {
#pragma unroll
      for (int pass = 0; pass < 4; ++pass)
#pragma unroll
        for (int hf = 0; hf < 2; ++hf)
          pf[pass * 2 + hf] = *(const float4*)(
              xb + (size_t)(pass * 32 + r) * NPIX + (T + 1) * 64 + hf * 32 + c4);
    }
    __syncthreads();  // barrier B: xnT reads done (next L may overwrite)
    const unsigned short* wbase = wbf2 + (size_t)(wv * 24) * 512 + lane * 8;
    {  // phase Q: q MFMA (mt 0,1) -> in-register no-max softmax -> direct store
      f32x4 aq[2][4];
#pragma unroll
      for (int i = 0; i < 2; ++i)
#pragma unroll
        for (int j = 0; j < 4; ++j)
#pragma unroll
          for (int q = 0; q < 4; ++q) aq[i][j][q] = 0.f;
#pragma unroll
      for (int mt = 0; mt < 2; ++mt)
#pragma unroll
        for (int ks = 0; ks < 4; ++ks) {
          const short8 af = *(const short8*)(wbase + (size_t)(mt * 4 + ks) * 512);
#pragma unroll
          for (int nt = 0; nt < 4; ++nt)
            aq[mt][nt] = __builtin_amdgcn_mfma_f32_16x16x32_bf16(af, bfr[ks][nt], aq[mt][nt], 0, 0, 0);
        }
#pragma unroll
      for (int nt = 0; nt < 4; ++nt) {
        float qv[8];
#pragma unroll
        for (int j = 0; j < 8; ++j) qv[j] = aq[j >> 2][nt][j & 3] * iv[nt];
        // softmax over d WITHOUT max-subtract: |q| <~ 3, exp safe in fp32
        float s = 0.f;
#pragma unroll
        for (int j = 0; j < 8; ++j) { qv[j] = __expf(qv[j]); s += qv[j]; }
        s += __shfl_xor(s, 16);
        s += __shfl_xor(s, 32);
        const float rs = SCALE / s;
        const int tile32 = T * 2 + (nt >> 1);
        if (WSQ) {
          uint4 qo;
          qo.x = (unsigned)f2bf(qv[0] * rs) | ((unsigned)f2bf(qv[1] * rs) << 16);
          qo.y = (unsigned)f2bf(qv[2] * rs) | ((unsigned)f2bf(qv[3] * rs) << 16);
          qo.z = (unsigned)f2bf(qv[4] * rs) | ((unsigned)f2bf(qv[5] * rs) << 16);
          qo.w = (unsigned)f2bf(qv[6] * rs) | ((unsigned)f2bf(qv[7] * rs) << 16);
          *(uint4*)(qb16 +
              ((((size_t)(b * NTILE + tile32) * 4 + wv) * 2 + (nt & 1)) * 64 + lane) * 8) = qo;
        } else {
#pragma unroll
          for (int j = 0; j < 8; ++j) {
            const int d = (j >> 2) * 16 + lg * 4 + (j & 3);
            qf32[((size_t)b * 128 + wv * 32 + d) * NPIX + tile32 * 32 + (nt & 1) * 16 + lr] = qv[j] * rs;
          }
        }
      }
    }
    {  // phase KV: k/v MFMA (mt 2..5), transient accs, packed b32 stores
#pragma unroll
      for (int mt = 2; mt < 6; ++mt) {
        f32x4 a[4];
#pragma unroll
        for (int j = 0; j < 4; ++j) a[j] = (f32x4){0.f, 0.f, 0.f, 0.f};
#pragma unroll
        for (int ks = 0; ks < 4; ++ks) {
          const short8 af = *(const short8*)(wbase + (size_t)(mt * 4 + ks) * 512);
#pragma unroll
          for (int nt = 0; nt < 4; ++nt)
            a[nt] = __builtin_amdgcn_mfma_f32_16x16x32_bf16(af, bfr[ks][nt], a[nt], 0, 0, 0);
        }
        // interleaved px-pair pack per half: col hf*32 + lr*2 = {px hf*32+lr, hf*32+16+lr}
#pragma unroll
        for (int q = 0; q < 4; ++q) {
          const int row_l = (mt - 2) * 16 + lg * 4 + q;   // k: 0..31, v: 32..63
          const unsigned pk01 = (unsigned)f2bf(a[0][q] * iv[0])
                              | ((unsigned)f2bf(a[1][q] * iv[1]) << 16);
          const unsigned pk23 = (unsigned)f2bf(a[2][q] * iv[2])
                              | ((unsigned)f2bf(a[3][q] * iv[3]) << 16);
          *(unsigned*)&kv_w[row_l * 72 + lr * 2] = pk01;
          *(unsigned*)&kv_w[row_l * 72 + 32 + lr * 2] = pk23;
        }
      }
    }
    // no barrier: kv rows are wave-private; same-wave LDS W->R ordered by HW
    {  // phase E/X: exp(k) on A-frags + ctx MFMA (slot order = stored order)
      short8 afk[2][2];
#pragma unroll
      for (int dt = 0; dt < 2; ++dt) {
        float s = 0.f;
#pragma unroll
        for (int hf = 0; hf < 2; ++hf) {
          const short8 kraw = *(const short8*)&kv_w[(dt * 16 + lr) * 72 + hf * 32 + lg * 8];
          short8 e16;
#pragma unroll
          for (int j = 0; j < 8; ++j) {
            const float ev = __expf(bf2f((unsigned short)kraw[j]));
            e16[j] = (short)f2bf(ev);
            s += ev;
          }
          afk[dt][hf] = e16;
        }
        s += __shfl_xor(s, 16);
        s += __shfl_xor(s, 32);
        se_row[dt] += s;
      }
#pragma unroll
      for (int dt = 0; dt < 2; ++dt)
#pragma unroll
        for (int et = 0; et < 2; ++et)
#pragma unroll
          for (int hf = 0; hf < 2; ++hf) {
            const short8 bf = *(const short8*)&kv_w[(32 + et * 16 + lr) * 72 + hf * 32 + lg * 8];
            ctx[dt][et] = __builtin_amdgcn_mfma_f32_16x16x32_bf16(afk[dt][hf], bf, ctx[dt][et], 0, 0, 0);
          }
    }
    // next L overwrites xnT only after barriers A/B of the next iteration
  }

  if (WSQ) {
    float* dst = ctx_dst + ((size_t)(b * NBLK + blk)) * 4096 + wv * 1024;
#pragma unroll
    for (int dt = 0; dt < 2; ++dt)
#pragma unroll
      for (int et = 0; et < 2; ++et)
#pragma unroll
        for (int q = 0; q < 4; ++q)
          dst[(dt * 16 + lg * 4 + q) * 32 + et * 16 + lr] = ctx[dt][et][q];
    if (lg == 0) {
#pragma unroll
      for (int dt = 0; dt < 2; ++dt)
        se_dst[(b * NBLK + blk) * 128 + wv * 32 + dt * 16 + lr] = se_row[dt];
    }
  } else {
#pragma unroll
    for (int dt = 0; dt < 2; ++dt)
#pragma unroll
      for (int et = 0; et < 2; ++et)
#pragma unroll
        for (int q = 0; q < 4; ++q)
          atomicAdd(&ctx_dst[((size_t)b * 128 + wv * 32 + dt * 16 + lg * 4 + q) * 32 + et * 16 + lr],
                    ctx[dt][et][q]);
    if (lg == 0) {
#pragma unroll
      for (int dt = 0; dt < 2; ++dt)
        atomicAdd(&se_dst[b * 128 + wv * 32 + dt * 16 + lr], se_row[dt]);
    }
  }
}

// Reduce NBLK partials + mem_kv -> normalized bf16 ctx, d-PERMUTED columns:
// ctxnT[b][h][e][c] where c = ((d>>2)&3)*8 + ((d>>4)&1)*4 + (d&3).
__global__ __launch_bounds__(256) void k_reduce(
    const float* __restrict__ part_ctx, const float* __restrict__ part_se,
    const float* __restrict__ mem_kv, unsigned short* __restrict__ ctxnT) {
  const int bid = blockIdx.x;
  const int b = bid >> 4, h = (bid >> 2) & 3, dq = bid & 3;
  const int t = threadIdx.x;
  const int dd = t >> 5;
  const int d = dq * 8 + dd;
  const int e = t & 31;
  __shared__ float sise[8];

  const float* mk = mem_kv + h * 128 + d * 4;
  const float* mv = mem_kv + 512 + h * 128 + e * 4;
  float ek[4];
  float acc = 0.f;
#pragma unroll
  for (int j = 0; j < 4; ++j) ek[j] = __expf(mk[j]);
#pragma unroll
  for (int j = 0; j < 4; ++j) acc += ek[j] * mv[j];
  const float* src = part_ctx + (size_t)b * NBLK * 4096 + h * 1024 + d * 32 + e;
  for (int p = 0; p < NBLK; ++p) acc += src[(size_t)p * 4096];
  if (e == 0) {
    float se = ek[0] + ek[1] + ek[2] + ek[3];
    const float* sp = part_se + (size_t)b * NBLK * 128 + h * 32 + d;
    for (int p = 0; p < NBLK; ++p) se += sp[(size_t)p * 128];
    sise[dd] = 1.f / se;
  }
  __syncthreads();
  const int c = ((d >> 2) & 3) * 8 + ((d >> 4) & 1) * 4 + (d & 3);
  ctxnT[(size_t)(b * 4 + h) * 1024 + e * 32 + c] = f2bf(acc * sise[dd]);
}

// Fallback-path normalizer: ctxG/seG (f32) -> ctxnT bf16 (same d-permutation)
__global__ __launch_bounds__(256) void k_norm(
    const float* __restrict__ ctxG, const float* __restrict__ seG,
    unsigned short* __restrict__ ctxnT) {
  const int b = blockIdx.x;
  const int t = threadIdx.x;
  const int h = t >> 6, d = (t >> 1) & 31, e0 = (t & 1) * 16;
  const int r = h * 32 + d;
  const float ise = 1.f / seG[b * 128 + r];
  const float* src = ctxG + ((size_t)b * 128 + r) * 32;
  unsigned short* dst = ctxnT + ((size_t)(b * 4 + h) * 32) * 32;
  const int c = ((d >> 2) & 3) * 8 + ((d >> 4) & 1) * 4 + (d & 3);
#pragma unroll
  for (int i = 0; i < 16; ++i)
    dst[(e0 + i) * 32 + c] = f2bf(src[e0 + i] * ise);
}

// Primary k3: q fragment-direct from qbf; out-proj A from owb2.
__global__ __launch_bounds__(256) void k3_ws(
    const unsigned short* __restrict__ ctxnT, const unsigned short* __restrict__ owb2,
    const unsigned short* __restrict__ qbf, const float* __restrict__ out_b,
    const float* __restrict__ out_norm_g, float* __restrict__ out) {
  __shared__ __align__(16) unsigned char smem[8704 + 2048 + 128];
  unsigned short* o1T = (unsigned short*)smem;     // [32 px][136 ch]
  float* redu = (float*)(smem + 8704);             // [16][32]
  float* inv = (float*)(smem + 8704 + 2048);       // [32]

  const int t = threadIdx.x;
  const int b = blockIdx.y;
  const int tile = blockIdx.x;
  const int p0 = tile * 32;
  const int wv = t >> 6;
  const int lane = t & 63;
  const int lr = lane & 15;
  const int lg = lane >> 4;

  {  // step 1: head wv: o1[e][p] = sum_d ctxn[e][d] * q[p][h*32+d]
    f32x4 o1a[2][2];
#pragma unroll
    for (int i = 0; i < 2; ++i)
#pragma unroll
      for (int j = 0; j < 2; ++j)
#pragma unroll
        for (int q = 0; q < 4; ++q) o1a[i][j][q] = 0.f;
    const unsigned short* cbase = ctxnT + (size_t)(b * 4 + wv) * 1024;
    const unsigned short* qb = qbf + (((size_t)(b * NTILE + tile) * 4 + wv) * 2) * 512;
    short8 bq[2];
#pragma unroll
    for (int nt = 0; nt < 2; ++nt)
      bq[nt] = *(const short8*)(qb + (size_t)(nt * 64 + lane) * 8);
#pragma unroll
    for (int mt = 0; mt < 2; ++mt) {
      const short8 af = *(const short8*)(cbase + (mt * 16 + lr) * 32 + lg * 8);
#pragma unroll
      for (int nt = 0; nt < 2; ++nt)
        o1a[mt][nt] = __builtin_amdgcn_mfma_f32_16x16x32_bf16(af, bq[nt], o1a[mt][nt], 0, 0, 0);
    }
#pragma unroll
    for (int mt = 0; mt < 2; ++mt)
#pragma unroll
      for (int nt = 0; nt < 2; ++nt)
#pragma unroll
        for (int q = 0; q < 4; ++q) {
          const int e = wv * 32 + mt * 16 + lg * 4 + q;
          o1T[(nt * 16 + lr) * 136 + e] = f2bf(o1a[mt][nt][q]);
        }
  }
  __syncthreads();
  // step 2: y[o][p] for o in [32*wv, +32); A from fragment-ordered owb2
  f32x4 y[2][2];
#pragma unroll
  for (int i = 0; i < 2; ++i)
#pragma unroll
    for (int j = 0; j < 2; ++j)
#pragma unroll
      for (int q = 0; q < 4; ++q) y[i][j][q] = 0.f;
  const unsigned short* wbase = owb2 + (size_t)(wv * 8) * 512 + lane * 8;
#pragma unroll
  for (int mt = 0; mt < 2; ++mt) {
#pragma unroll
    for (int ks = 0; ks < 4; ++ks) {
      const short8 af = *(const short8*)(wbase + (size_t)(mt * 4 + ks) * 512);
#pragma unroll
      for (int nt = 0; nt < 2; ++nt) {
        const short8 bf = *(const short8*)&o1T[(nt * 16 + lr) * 136 + ks * 32 + lg * 8];
        y[mt][nt] = __builtin_amdgcn_mfma_f32_16x16x32_bf16(af, bf, y[mt][nt], 0, 0, 0);
      }
    }
  }
  {
    float ss[2] = {0.f, 0.f};
#pragma unroll
    for (int mt = 0; mt < 2; ++mt)
#pragma unroll
      for (int q = 0; q < 4; ++q) {
        const int row = 32 * wv + mt * 16 + lg * 4 + q;
        const float bb = out_b[row];
#pragma unroll
        for (int nt = 0; nt < 2; ++nt) {
          y[mt][nt][q] += bb;
          ss[nt] = fmaf(y[mt][nt][q], y[mt][nt][q], ss[nt]);
        }
      }
#pragma unroll
    for (int nt = 0; nt < 2; ++nt)
      redu[(wv * 4 + lg) * 32 + nt * 16 + lr] = ss[nt];
  }
  __syncthreads();
  if (t < 32) {
    float s = 0.f;
#pragma unroll
    for (int g = 0; g < 16; ++g) s += redu[g * 32 + t];
    inv[t] = SQRT128 / fmaxf(sqrtf(s), 1e-12f);
  }
  __syncthreads();
  {
    float* ob = out + (size_t)b * 128 * NPIX + p0;
#pragma unroll
    for (int mt = 0; mt < 2; ++mt)
#pragma unroll
      for (int q = 0; q < 4; ++q) {
        const int row = 32 * wv + mt * 16 + lg * 4 + q;
        const float g = out_norm_g[row];
#pragma unroll
        for (int nt = 0; nt < 2; ++nt) {
          const int col = nt * 16 + lr;
          ob[(size_t)row * NPIX + col] = y[mt][nt][q] * inv[col] * g;
        }
      }
  }
}

// Fallback k3: q f32 from d_out; qT written with the d-permutation so the
// canonical B-frag read matches the permuted ctxnT.
__global__ __launch_bounds__(256) void k3f(
    const unsigned short* __restrict__ ctxnT, const unsigned short* __restrict__ owb2,
    const float* __restrict__ out_b, const float* __restrict__ out_norm_g,
    float* __restrict__ io) {
  __shared__ __align__(16) unsigned char smem[8704 + 8704 + 2048 + 128];
  unsigned short* qT = (unsigned short*)smem;
  unsigned short* o1T = (unsigned short*)(smem + 8704);
  float* redu = (float*)(smem + 8704 + 8704);
  float* inv = (float*)(smem + 8704 + 8704 + 2048);

  const int t = threadIdx.x;
  const int b = blockIdx.y;
  const int p0 = blockIdx.x * 32;
  const int wv = t >> 6;
  const int lane = t & 63;
  const int lr = lane & 15;
  const int lg = lane >> 4;

  {
    const float* qb = io + (size_t)b * 128 * NPIX + p0;
    const int r = t >> 3, c4 = (t & 7) * 4;
#pragma unroll
    for (int pass = 0; pass < 4; ++pass) {
      const int row = pass * 32 + r;
      const int dl = row & 31;
      const int pc = (row & ~31) | (((dl >> 2) & 3) * 8 + ((dl >> 4) & 1) * 4 + (dl & 3));
      const float4 v = *(const float4*)(qb + (size_t)row * NPIX + c4);
      qT[(c4 + 0) * 136 + pc] = f2bf(v.x);
      qT[(c4 + 1) * 136 + pc] = f2bf(v.y);
      qT[(c4 + 2) * 136 + pc] = f2bf(v.z);
      qT[(c4 + 3) * 136 + pc] = f2bf(v.w);
    }
  }
  __syncthreads();
  {
    f32x4 o1a[2][2];
#pragma unroll
    for (int i = 0; i < 2; ++i)
#pragma unroll
      for (int j = 0; j < 2; ++j)
#pragma unroll
        for (int q = 0; q < 4; ++q) o1a[i][j][q] = 0.f;
    const unsigned short* cbase = ctxnT + (size_t)(b * 4 + wv) * 1024;
#pragma unroll
    for (int mt = 0; mt < 2; ++mt) {
      const short8 af = *(const short8*)(cbase + (mt * 16 + lr) * 32 + lg * 8);
#pragma unroll
      for (int nt = 0; nt < 2; ++nt) {
        const short8 bf = *(const short8*)&qT[(nt * 16 + lr) * 136 + wv * 32 + lg * 8];
        o1a[mt][nt] = __builtin_amdgcn_mfma_f32_16x16x32_bf16(af, bf, o1a[mt][nt], 0, 0, 0);
      }
    }
#pragma unroll
    for (int mt = 0; mt < 2; ++mt)
#pragma unroll
      for (int nt = 0; nt < 2; ++nt)
#pragma unroll
        for (int q = 0; q < 4; ++q) {
          const int e = wv * 32 + mt * 16 + lg * 4 + q;
          o1T[(nt * 16 + lr) * 136 + e] = f2bf(o1a[mt][nt][q]);
        }
  }
  __syncthreads();
  f32x4 y[2][2];
#pragma unroll
  for (int i = 0; i < 2; ++i)
#pragma unroll
    for (int j = 0; j < 2; ++j)
#pragma unroll
      for (int q = 0; q < 4; ++q) y[i][j][q] = 0.f;
  const unsigned short* wbase = owb2 + (size_t)(wv * 8) * 512 + lane * 8;
#pragma unroll
  for (int mt = 0; mt < 2; ++mt) {
#pragma unroll
    for (int ks = 0; ks < 4; ++ks) {
      const short8 af = *(const short8*)(wbase + (size_t)(mt * 4 + ks) * 512);
#pragma unroll
      for (int nt = 0; nt < 2; ++nt) {
        const short8 bf = *(const short8*)&o1T[(nt * 16 + lr) * 136 + ks * 32 + lg * 8];
        y[mt][nt] = __builtin_amdgcn_mfma_f32_16x16x32_bf16(af, bf, y[mt][nt], 0, 0, 0);
      }
    }
  }
  {
    float ss[2] = {0.f, 0.f};
#pragma unroll
    for (int mt = 0; mt < 2; ++mt)
#pragma unroll
      for (int q = 0; q < 4; ++q) {
        const int row = 32 * wv + mt * 16 + lg * 4 + q;
        const float bb = out_b[row];
#pragma unroll
        for (int nt = 0; nt < 2; ++nt) {
          y[mt][nt][q] += bb;
          ss[nt] = fmaf(y[mt][nt][q], y[mt][nt][q], ss[nt]);
        }
      }
#pragma unroll
    for (int nt = 0; nt < 2; ++nt)
      redu[(wv * 4 + lg) * 32 + nt * 16 + lr] = ss[nt];
  }
  __syncthreads();
  if (t < 32) {
    float s = 0.f;
#pragma unroll
    for (int g = 0; g < 16; ++g) s += redu[g * 32 + t];
    inv[t] = SQRT128 / fmaxf(sqrtf(s), 1e-12f);
  }
  __syncthreads();
  {
    float* ob = io + (size_t)b * 128 * NPIX + p0;
#pragma unroll
    for (int mt = 0; mt < 2; ++mt)
#pragma unroll
      for (int q = 0; q < 4; ++q) {
        const int row = 32 * wv + mt * 16 + lg * 4 + q;
        const float g = out_norm_g[row];
#pragma unroll
        for (int nt = 0; nt < 2; ++nt) {
          const int col = nt * 16 + lr;
          ob[(size_t)row * NPIX + col] = y[mt][nt][q] * inv[col] * g;
        }
      }
  }
}

extern "C" void kernel_launch(void* const* d_in, const int* in_sizes, int n_in,
                              void* d_out, int out_size, void* d_ws, size_t ws_size,
                              hipStream_t stream) {
  const float* x          = (const float*)d_in[0];
  const float* norm_g     = (const float*)d_in[1];
  const float* qkv_w      = (const float*)d_in[2];
  const float* mem_kv     = (const float*)d_in[3];
  const float* out_w      = (const float*)d_in[4];
  const float* out_b      = (const float*)d_in[5];
  const float* out_norm_g = (const float*)d_in[6];
  float* out = (float*)d_out;

  const size_t PC = (size_t)16 * NBLK * 4096;   // f32 units
  const size_t PS = (size_t)16 * NBLK * 128;    // f32 units
  const size_t QB = (size_t)16 * NPIX * 128;    // u16 units
  const size_t need = (PC + PS) * 4 + (49152 + 16384 + 65536 + QB) * 2;

  if (ws_size >= need) {
    float* part_ctx = (float*)d_ws;
    float* part_se  = part_ctx + PC;
    unsigned short* wbf2  = (unsigned short*)(part_se + PS);
    unsigned short* owb2  = wbf2 + 49152;
    unsigned short* ctxnT = owb2 + 16384;
    unsigned short* qbf   = ctxnT + 65536;
    k_prep2<<<32, 256, 0, stream>>>(qkv_w, norm_g, out_w, wbf2, owb2);
    k1<true><<<dim3(NBLK, 16), 256, 0, stream>>>(x, wbf2, qbf, nullptr, part_ctx, part_se);
    k_reduce<<<256, 256, 0, stream>>>(part_ctx, part_se, mem_kv, ctxnT);
    k3_ws<<<dim3(NTILE, 16), 256, 0, stream>>>(ctxnT, owb2, qbf, out_b, out_norm_g, out);
  } else {
    float* ctxG = (float*)d_ws;                  // 65536 f32
    float* seG  = ctxG + 65536;                  // 2048 f32
    unsigned short* wbf2  = (unsigned short*)(seG + 2048);
    unsigned short* owb2  = wbf2 + 49152;
    unsigned short* ctxnT = owb2 + 16384;
    k_prep2<<<32, 256, 0, stream>>>(qkv_w, norm_g, out_w, wbf2, owb2);
    k_init<<<64, 256, 0, stream>>>(mem_kv, ctxG, seG);
    k1<false><<<dim3(NBLK, 16), 256, 0, stream>>>(x, wbf2, nullptr, out, ctxG, seG);
    k_norm<<<16, 256, 0, stream>>>(ctxG, seG, ctxnT);
    k3f<<<dim3(NTILE, 16), 256, 0, stream>>>(ctxnT, owb2, out_b, out_norm_g, out);
  }
}

// Round 16
// 69.150 us; speedup vs baseline: 1.1443x; 1.1443x over previous
//
#include <hip/hip_runtime.h>
#include <hip/hip_bf16.h>
#include <math.h>

#define NPIX 9216
#define NBLK 48          // k1 blocks per batch (grid 768 = 3/CU exactly)
#define TPB 6            // pixel-tiles (32px) per k1 block
#define NTILE 288        // pixel tiles per batch
#define SCALE 0.17677669529663687f   // 32^-0.5
#define SQRT128 11.313708498984761f

typedef __attribute__((ext_vector_type(8))) short short8;
typedef __attribute__((ext_vector_type(4))) float f32x4;

static __device__ __forceinline__ unsigned short f2bf(float f) {
  return __bfloat16_as_ushort(__float2bfloat16(f));
}
static __device__ __forceinline__ float bf2f(unsigned short h) {
  return __bfloat162float(__ushort_as_bfloat16(h));
}

// d-permutation: q's B-fragment k-slot j at lane-group lg holds channel
// d = (j>>2)*16 + lg*4 + (j&3). ctxnT's d-columns stored in the same slot
// order: col c = ((d>>2)&3)*8 + ((d>>4)&1)*4 + (d&3). A/B pair slot-to-slot.

// Primary ws layout:
//   part_ctx f32[16][NBLK][4096]
//   part_se  f32[16][NBLK][128]
//   wbf2  bf16[96 groups][64 lanes][8]   (qkv_w*norm_g, fragment order, HEAD-major)
//   owb2  bf16[32 groups][64 lanes][8]   (out_w, fragment order)
//   ctxnT bf16[16][4][32][32]            ([b][h][e][dperm], normalized)
//   qbf   bf16[16][NTILE][4][2][64][8]   (softmaxed q, B-fragment order, dperm slots)

__global__ __launch_bounds__(256) void k_prep2(
    const float* __restrict__ qkv_w, const float* __restrict__ norm_g,
    const float* __restrict__ out_w,
    unsigned short* __restrict__ wbf2, unsigned short* __restrict__ owb2) {
  const int i = blockIdx.x * 256 + threadIdx.x;
  if (i < 6144) {              // wbf2: 96 groups x 64 lanes, head-major rows
    const int g = i >> 6, lane = i & 63;
    const int wv = g / 24, rem = g % 24;   // g = (wv*6+mt)*4+ks
    const int mt = rem >> 2, ks = rem & 3;
    const int row = (mt >> 1) * 128 + wv * 32 + (mt & 1) * 16 + (lane & 15);
    const int col = ks * 32 + (lane >> 4) * 8;
    const float* src = qkv_w + row * 128 + col;
    const float* gg = norm_g + col;
    uint4 o;
    o.x = (unsigned)f2bf(src[0] * gg[0]) | ((unsigned)f2bf(src[1] * gg[1]) << 16);
    o.y = (unsigned)f2bf(src[2] * gg[2]) | ((unsigned)f2bf(src[3] * gg[3]) << 16);
    o.z = (unsigned)f2bf(src[4] * gg[4]) | ((unsigned)f2bf(src[5] * gg[5]) << 16);
    o.w = (unsigned)f2bf(src[6] * gg[6]) | ((unsigned)f2bf(src[7] * gg[7]) << 16);
    *(uint4*)(wbf2 + (size_t)i * 8) = o;
  } else if (i < 8192) {       // owb2: 32 groups x 64 lanes
    const int i2 = i - 6144;
    const int g = i2 >> 6, lane = i2 & 63;  // g = (wv*2+mt)*4+ks
    const int wv = g >> 3, rem = g & 7;
    const int mt = rem >> 2, ks = rem & 3;
    const int row = 32 * wv + mt * 16 + (lane & 15);
    const int col = ks * 32 + (lane >> 4) * 8;
    const float* src = out_w + row * 128 + col;
    uint4 o;
    o.x = (unsigned)f2bf(src[0]) | ((unsigned)f2bf(src[1]) << 16);
    o.y = (unsigned)f2bf(src[2]) | ((unsigned)f2bf(src[3]) << 16);
    o.z = (unsigned)f2bf(src[4]) | ((unsigned)f2bf(src[5]) << 16);
    o.w = (unsigned)f2bf(src[6]) | ((unsigned)f2bf(src[7]) << 16);
    *(uint4*)(owb2 + (size_t)i2 * 8) = o;
  }
}

// fallback-path ctx init from mem_kv
__global__ __launch_bounds__(256) void k_init(const float* __restrict__ mem_kv,
                                              float* __restrict__ ctxG,
                                              float* __restrict__ sumexpG) {
  const int bh = blockIdx.x;
  const int h = bh & 3;
  const float* mk = mem_kv + h * 128;
  const float* mv = mem_kv + 512 + h * 128;
  const int t = threadIdx.x;
  const int d = t >> 3, e0 = (t & 7) * 4;
  float ek[4], se = 0.f;
#pragma unroll
  for (int j = 0; j < 4; ++j) { ek[j] = __expf(mk[d * 4 + j]); se += ek[j]; }
#pragma unroll
  for (int ei = 0; ei < 4; ++ei) {
    const int e = e0 + ei;
    float s = 0.f;
#pragma unroll
    for (int j = 0; j < 4; ++j) s += ek[j] * mv[e * 4 + j];
    ctxG[(bh * 32 + d) * 32 + e] = s;
  }
  if ((t & 7) == 0) sumexpG[bh * 32 + d] = se;
}

// Fused MFMA k1 (round-14 best: 32px tiles, grid 768, kv-packed b32,
// in-register q softmax, weight-stationary wreg with full static indexing).
// Rounds 10-15 established k1's ~46-48us is a structural per-tile serial
// spine for this decomposition: barriers(r10)/occupancy(r11)/LDS-ops(r12)/
// weight-residency(r14)/tile-size(r15) all null or negative.
template <bool WSQ>
__global__ __launch_bounds__(256, 2) void k1(
    const float* __restrict__ x, const unsigned short* __restrict__ wbf2,
    unsigned short* __restrict__ qb16, float* __restrict__ qf32,
    float* __restrict__ ctx_dst, float* __restrict__ se_dst) {
  __shared__ __align__(16) unsigned char smem[20480 + 17408 + 4096];
  unsigned short* kv = (unsigned short*)smem;                   // [4][64][40]
  unsigned short* xnT0 = (unsigned short*)(smem + 20480);       // [2][32][136]
  float* redu0 = (float*)(smem + 20480 + 17408);                // [2][16][32]

  const int t = threadIdx.x;
  const int b = blockIdx.y;
  const int blk = blockIdx.x;
  const int wv = t >> 6;
  const int lane = t & 63;
  const int lr = lane & 15;
  const int lg = lane >> 4;
  const int r = t >> 3, c4 = (t & 7) * 4;
  const float* xb = x + ((size_t)b * 128) * NPIX + blk * TPB * 32;
  unsigned short* kv_w = kv + wv * 64 * 40;   // this wave's private k/v region

  // prologue: weight fragments resident in registers for the whole kernel
  short8 wreg[24];
  {
    const unsigned short* wbase = wbf2 + (size_t)(wv * 24) * 512 + lane * 8;
#pragma unroll
    for (int g = 0; g < 24; ++g)
      wreg[g] = *(const short8*)(wbase + (size_t)g * 512);
  }

  f32x4 ctx[2][2];
#pragma unroll
  for (int i = 0; i < 2; ++i)
#pragma unroll
    for (int j = 0; j < 2; ++j)
#pragma unroll
      for (int q = 0; q < 4; ++q) ctx[i][j][q] = 0.f;
  float se_row[2] = {0.f, 0.f};

  float4 pf[4];   // prefetched x tile (4 rows x 4 px per thread)
#pragma unroll
  for (int pass = 0; pass < 4; ++pass)
    pf[pass] = *(const float4*)(xb + (size_t)(pass * 32 + r) * NPIX + c4);

  for (int it = 0; it < TPB; ++it) {
    const int tile = blk * TPB + it;
    unsigned short* xnT = xnT0 + (it & 1) * 4352;   // 8704B buffers
    float* redu = redu0 + (it & 1) * 512;           // 2KB buffers

    {  // phase L: regs -> bf16 transpose into xnT[buf] + paired sumsq partials
      float ss0 = 0.f, ss1 = 0.f, ss2 = 0.f, ss3 = 0.f;
#pragma unroll
      for (int pass = 0; pass < 4; ++pass) {
        const int row = pass * 32 + r;
        const float4 v = pf[pass];
        xnT[(c4 + 0) * 136 + row] = f2bf(v.x);
        xnT[(c4 + 1) * 136 + row] = f2bf(v.y);
        xnT[(c4 + 2) * 136 + row] = f2bf(v.z);
        xnT[(c4 + 3) * 136 + row] = f2bf(v.w);
        ss0 = fmaf(v.x, v.x, ss0); ss1 = fmaf(v.y, v.y, ss1);
        ss2 = fmaf(v.z, v.z, ss2); ss3 = fmaf(v.w, v.w, ss3);
      }
      // pre-reduce row pairs (t ^ 8 has r^1, same pixels) -> redu[16][32]
      ss0 += __shfl_xor(ss0, 8); ss1 += __shfl_xor(ss1, 8);
      ss2 += __shfl_xor(ss2, 8); ss3 += __shfl_xor(ss3, 8);
      if (!(t & 8))
        *(float4*)&redu[(t >> 4) * 32 + c4] = make_float4(ss0, ss1, ss2, ss3);
    }
    __syncthreads();  // THE barrier: xnT[buf] + redu[buf] visible
    float iv0, iv1;
    {  // per-wave inv (redundant x4): lanes 0..31 sum redu col, shfl broadcast
      float invv = 0.f;
      if (lane < 32) {
        float s = 0.f;
#pragma unroll
        for (int g = 0; g < 16; ++g) s += redu[g * 32 + lane];
        invv = SQRT128 / fmaxf(sqrtf(s), 1e-12f);
      }
      iv0 = __shfl(invv, lr);
      iv1 = __shfl(invv, 16 + lr);
    }
    short8 bfr[4][2];
#pragma unroll
    for (int ks = 0; ks < 4; ++ks)
#pragma unroll
      for (int nt = 0; nt < 2; ++nt)
        bfr[ks][nt] = *(const short8*)&xnT[(nt * 16 + lr) * 136 + ks * 32 + lg * 8];
    if (it + 1 < TPB) {
      const float* xb2 = xb + (it + 1) * 32;
#pragma unroll
      for (int pass = 0; pass < 4; ++pass)
        pf[pass] = *(const float4*)(xb2 + (size_t)(pass * 32 + r) * NPIX + c4);
    }
    {  // phase Q: q MFMA (mt 0,1) -> in-register softmax -> direct store
      f32x4 aq[2][2];
#pragma unroll
      for (int i = 0; i < 2; ++i)
#pragma unroll
        for (int j = 0; j < 2; ++j)
#pragma unroll
          for (int q = 0; q < 4; ++q) aq[i][j][q] = 0.f;
#pragma unroll
      for (int mt = 0; mt < 2; ++mt)
#pragma unroll
        for (int ks = 0; ks < 4; ++ks) {
          const short8 af = wreg[mt * 4 + ks];
          aq[mt][0] = __builtin_amdgcn_mfma_f32_16x16x32_bf16(af, bfr[ks][0], aq[mt][0], 0, 0, 0);
          aq[mt][1] = __builtin_amdgcn_mfma_f32_16x16x32_bf16(af, bfr[ks][1], aq[mt][1], 0, 0, 0);
        }
      // softmax over d (32 rows spread over lg x mt x q) per px column
#pragma unroll
      for (int nt = 0; nt < 2; ++nt) {
        const float iv = nt ? iv1 : iv0;
        float qv[8];
#pragma unroll
        for (int j = 0; j < 8; ++j) qv[j] = aq[j >> 2][nt][j & 3] * iv;
        float m = qv[0];
#pragma unroll
        for (int j = 1; j < 8; ++j) m = fmaxf(m, qv[j]);
        m = fmaxf(m, __shfl_xor(m, 16));
        m = fmaxf(m, __shfl_xor(m, 32));
        float s = 0.f;
#pragma unroll
        for (int j = 0; j < 8; ++j) { qv[j] = __expf(qv[j] - m); s += qv[j]; }
        s += __shfl_xor(s, 16);
        s += __shfl_xor(s, 32);
        const float rs = SCALE / s;
        if (WSQ) {
          uint4 qo;
          qo.x = (unsigned)f2bf(qv[0] * rs) | ((unsigned)f2bf(qv[1] * rs) << 16);
          qo.y = (unsigned)f2bf(qv[2] * rs) | ((unsigned)f2bf(qv[3] * rs) << 16);
          qo.z = (unsigned)f2bf(qv[4] * rs) | ((unsigned)f2bf(qv[5] * rs) << 16);
          qo.w = (unsigned)f2bf(qv[6] * rs) | ((unsigned)f2bf(qv[7] * rs) << 16);
          *(uint4*)(qb16 +
              ((((size_t)(b * NTILE + tile) * 4 + wv) * 2 + nt) * 64 + lane) * 8) = qo;
        } else {
#pragma unroll
          for (int j = 0; j < 8; ++j) {
            const int d = (j >> 2) * 16 + lg * 4 + (j & 3);
            qf32[((size_t)b * 128 + wv * 32 + d) * NPIX + tile * 32 + nt * 16 + lr] = qv[j] * rs;
          }
        }
      }
    }
    {  // phase KV: k/v MFMA (mt 2..5), transient accs, FULL unroll (static wreg idx)
#pragma unroll
      for (int mt = 2; mt < 6; ++mt) {
        f32x4 a0 = {0.f, 0.f, 0.f, 0.f};
        f32x4 a1 = {0.f, 0.f, 0.f, 0.f};
#pragma unroll
        for (int ks = 0; ks < 4; ++ks) {
          const short8 af = wreg[mt * 4 + ks];
          a0 = __builtin_amdgcn_mfma_f32_16x16x32_bf16(af, bfr[ks][0], a0, 0, 0, 0);
          a1 = __builtin_amdgcn_mfma_f32_16x16x32_bf16(af, bfr[ks][1], a1, 0, 0, 0);
        }
        // interleaved px-pair pack: col lr*2 holds {px=lr, px=16+lr}
#pragma unroll
        for (int q = 0; q < 4; ++q) {
          const int row_l = (mt - 2) * 16 + lg * 4 + q;   // k: 0..31, v: 32..63
          const unsigned pk = (unsigned)f2bf(a0[q] * iv0)
                            | ((unsigned)f2bf(a1[q] * iv1) << 16);
          *(unsigned*)&kv_w[row_l * 40 + lr * 2] = pk;
        }
      }
    }
    // no barrier: kv rows are wave-private; same-wave LDS W->R ordered by HW
    {  // phase E/X: exp(k) on A-frags + ctx MFMA (slot order = stored order)
      short8 afk[2];
#pragma unroll
      for (int dt = 0; dt < 2; ++dt) {
        const short8 kraw = *(const short8*)&kv_w[(dt * 16 + lr) * 40 + lg * 8];
        short8 e16;
        float s = 0.f;
#pragma unroll
        for (int j = 0; j < 8; ++j) {
          const float ev = __expf(bf2f((unsigned short)kraw[j]));
          e16[j] = (short)f2bf(ev);
          s += ev;
        }
        afk[dt] = e16;
        s += __shfl_xor(s, 16);
        s += __shfl_xor(s, 32);
        se_row[dt] += s;
      }
#pragma unroll
      for (int dt = 0; dt < 2; ++dt)
#pragma unroll
        for (int et = 0; et < 2; ++et) {
          const short8 bf = *(const short8*)&kv_w[(32 + et * 16 + lr) * 40 + lg * 8];
          ctx[dt][et] = __builtin_amdgcn_mfma_f32_16x16x32_bf16(afk[dt], bf, ctx[dt][et], 0, 0, 0);
        }
    }
    // next L writes xnT[buf^1]/redu[buf^1] (disjoint), kv wave-private: no barrier
  }

  if (WSQ) {
    float* dst = ctx_dst + ((size_t)(b * NBLK + blk)) * 4096 + wv * 1024;
#pragma unroll
    for (int dt = 0; dt < 2; ++dt)
#pragma unroll
      for (int et = 0; et < 2; ++et)
#pragma unroll
        for (int q = 0; q < 4; ++q)
          dst[(dt * 16 + lg * 4 + q) * 32 + et * 16 + lr] = ctx[dt][et][q];
    if (lg == 0) {
#pragma unroll
      for (int dt = 0; dt < 2; ++dt)
        se_dst[(b * NBLK + blk) * 128 + wv * 32 + dt * 16 + lr] = se_row[dt];
    }
  } else {
#pragma unroll
    for (int dt = 0; dt < 2; ++dt)
#pragma unroll
      for (int et = 0; et < 2; ++et)
#pragma unroll
        for (int q = 0; q < 4; ++q)
          atomicAdd(&ctx_dst[((size_t)b * 128 + wv * 32 + dt * 16 + lg * 4 + q) * 32 + et * 16 + lr],
                    ctx[dt][et][q]);
    if (lg == 0) {
#pragma unroll
      for (int dt = 0; dt < 2; ++dt)
        atomicAdd(&se_dst[b * 128 + wv * 32 + dt * 16 + lr], se_row[dt]);
    }
  }
}

// Reduce NBLK partials + mem_kv -> normalized bf16 ctx, d-PERMUTED columns:
// ctxnT[b][h][e][c] where c = ((d>>2)&3)*8 + ((d>>4)&1)*4 + (d&3).
__global__ __launch_bounds__(256) void k_reduce(
    const float* __restrict__ part_ctx, const float* __restrict__ part_se,
    const float* __restrict__ mem_kv, unsigned short* __restrict__ ctxnT) {
  const int bid = blockIdx.x;
  const int b = bid >> 4, h = (bid >> 2) & 3, dq = bid & 3;
  const int t = threadIdx.x;
  const int dd = t >> 5;
  const int d = dq * 8 + dd;
  const int e = t & 31;
  __shared__ float sise[8];

  const float* mk = mem_kv + h * 128 + d * 4;
  const float* mv = mem_kv + 512 + h * 128 + e * 4;
  float ek[4];
  float acc = 0.f;
#pragma unroll
  for (int j = 0; j < 4; ++j) ek[j] = __expf(mk[j]);
#pragma unroll
  for (int j = 0; j < 4; ++j) acc += ek[j] * mv[j];
  const float* src = part_ctx + (size_t)b * NBLK * 4096 + h * 1024 + d * 32 + e;
  for (int p = 0; p < NBLK; ++p) acc += src[(size_t)p * 4096];
  if (e == 0) {
    float se = ek[0] + ek[1] + ek[2] + ek[3];
    const float* sp = part_se + (size_t)b * NBLK * 128 + h * 32 + d;
    for (int p = 0; p < NBLK; ++p) se += sp[(size_t)p * 128];
    sise[dd] = 1.f / se;
  }
  __syncthreads();
  const int c = ((d >> 2) & 3) * 8 + ((d >> 4) & 1) * 4 + (d & 3);
  ctxnT[(size_t)(b * 4 + h) * 1024 + e * 32 + c] = f2bf(acc * sise[dd]);
}

// Fallback-path normalizer: ctxG/seG (f32) -> ctxnT bf16 (same d-permutation)
__global__ __launch_bounds__(256) void k_norm(
    const float* __restrict__ ctxG, const float* __restrict__ seG,
    unsigned short* __restrict__ ctxnT) {
  const int b = blockIdx.x;
  const int t = threadIdx.x;
  const int h = t >> 6, d = (t >> 1) & 31, e0 = (t & 1) * 16;
  const int r = h * 32 + d;
  const float ise = 1.f / seG[b * 128 + r];
  const float* src = ctxG + ((size_t)b * 128 + r) * 32;
  unsigned short* dst = ctxnT + ((size_t)(b * 4 + h) * 32) * 32;
  const int c = ((d >> 2) & 3) * 8 + ((d >> 4) & 1) * 4 + (d & 3);
#pragma unroll
  for (int i = 0; i < 16; ++i)
    dst[(e0 + i) * 32 + c] = f2bf(src[e0 + i] * ise);
}

// Primary k3: q fragment-direct from qbf; out-proj A from owb2.
__global__ __launch_bounds__(256) void k3_ws(
    const unsigned short* __restrict__ ctxnT, const unsigned short* __restrict__ owb2,
    const unsigned short* __restrict__ qbf, const float* __restrict__ out_b,
    const float* __restrict__ out_norm_g, float* __restrict__ out) {
  __shared__ __align__(16) unsigned char smem[8704 + 2048 + 128];
  unsigned short* o1T = (unsigned short*)smem;     // [32 px][136 ch]
  float* redu = (float*)(smem + 8704);             // [16][32]
  float* inv = (float*)(smem + 8704 + 2048);       // [32]

  const int t = threadIdx.x;
  const int b = blockIdx.y;
  const int tile = blockIdx.x;
  const int p0 = tile * 32;
  const int wv = t >> 6;
  const int lane = t & 63;
  const int lr = lane & 15;
  const int lg = lane >> 4;

  {  // step 1: head wv: o1[e][p] = sum_d ctxn[e][d] * q[p][h*32+d]
    f32x4 o1a[2][2];
#pragma unroll
    for (int i = 0; i < 2; ++i)
#pragma unroll
      for (int j = 0; j < 2; ++j)
#pragma unroll
        for (int q = 0; q < 4; ++q) o1a[i][j][q] = 0.f;
    const unsigned short* cbase = ctxnT + (size_t)(b * 4 + wv) * 1024;
    const unsigned short* qb = qbf + (((size_t)(b * NTILE + tile) * 4 + wv) * 2) * 512;
    short8 bq[2];
#pragma unroll
    for (int nt = 0; nt < 2; ++nt)
      bq[nt] = *(const short8*)(qb + (size_t)(nt * 64 + lane) * 8);
#pragma unroll
    for (int mt = 0; mt < 2; ++mt) {
      const short8 af = *(const short8*)(cbase + (mt * 16 + lr) * 32 + lg * 8);
#pragma unroll
      for (int nt = 0; nt < 2; ++nt)
        o1a[mt][nt] = __builtin_amdgcn_mfma_f32_16x16x32_bf16(af, bq[nt], o1a[mt][nt], 0, 0, 0);
    }
#pragma unroll
    for (int mt = 0; mt < 2; ++mt)
#pragma unroll
      for (int nt = 0; nt < 2; ++nt)
#pragma unroll
        for (int q = 0; q < 4; ++q) {
          const int e = wv * 32 + mt * 16 + lg * 4 + q;
          o1T[(nt * 16 + lr) * 136 + e] = f2bf(o1a[mt][nt][q]);
        }
  }
  __syncthreads();
  // step 2: y[o][p] for o in [32*wv, +32); A from fragment-ordered owb2
  f32x4 y[2][2];
#pragma unroll
  for (int i = 0; i < 2; ++i)
#pragma unroll
    for (int j = 0; j < 2; ++j)
#pragma unroll
      for (int q = 0; q < 4; ++q) y[i][j][q] = 0.f;
  const unsigned short* wbase = owb2 + (size_t)(wv * 8) * 512 + lane * 8;
#pragma unroll
  for (int mt = 0; mt < 2; ++mt) {
#pragma unroll
    for (int ks = 0; ks < 4; ++ks) {
      const short8 af = *(const short8*)(wbase + (size_t)(mt * 4 + ks) * 512);
#pragma unroll
      for (int nt = 0; nt < 2; ++nt) {
        const short8 bf = *(const short8*)&o1T[(nt * 16 + lr) * 136 + ks * 32 + lg * 8];
        y[mt][nt] = __builtin_amdgcn_mfma_f32_16x16x32_bf16(af, bf, y[mt][nt], 0, 0, 0);
      }
    }
  }
  {
    float ss[2] = {0.f, 0.f};
#pragma unroll
    for (int mt = 0; mt < 2; ++mt)
#pragma unroll
      for (int q = 0; q < 4; ++q) {
        const int row = 32 * wv + mt * 16 + lg * 4 + q;
        const float bb = out_b[row];
#pragma unroll
        for (int nt = 0; nt < 2; ++nt) {
          y[mt][nt][q] += bb;
          ss[nt] = fmaf(y[mt][nt][q], y[mt][nt][q], ss[nt]);
        }
      }
#pragma unroll
    for (int nt = 0; nt < 2; ++nt)
      redu[(wv * 4 + lg) * 32 + nt * 16 + lr] = ss[nt];
  }
  __syncthreads();
  if (t < 32) {
    float s = 0.f;
#pragma unroll
    for (int g = 0; g < 16; ++g) s += redu[g * 32 + t];
    inv[t] = SQRT128 / fmaxf(sqrtf(s), 1e-12f);
  }
  __syncthreads();
  {
    float* ob = out + (size_t)b * 128 * NPIX + p0;
#pragma unroll
    for (int mt = 0; mt < 2; ++mt)
#pragma unroll
      for (int q = 0; q < 4; ++q) {
        const int row = 32 * wv + mt * 16 + lg * 4 + q;
        const float g = out_norm_g[row];
#pragma unroll
        for (int nt = 0; nt < 2; ++nt) {
          const int col = nt * 16 + lr;
          ob[(size_t)row * NPIX + col] = y[mt][nt][q] * inv[col] * g;
        }
      }
  }
}

// Fallback k3: q f32 from d_out; qT written with the d-permutation so the
// canonical B-frag read matches the permuted ctxnT.
__global__ __launch_bounds__(256) void k3f(
    const unsigned short* __restrict__ ctxnT, const unsigned short* __restrict__ owb2,
    const float* __restrict__ out_b, const float* __restrict__ out_norm_g,
    float* __restrict__ io) {
  __shared__ __align__(16) unsigned char smem[8704 + 8704 + 2048 + 128];
  unsigned short* qT = (unsigned short*)smem;
  unsigned short* o1T = (unsigned short*)(smem + 8704);
  float* redu = (float*)(smem + 8704 + 8704);
  float* inv = (float*)(smem + 8704 + 8704 + 2048);

  const int t = threadIdx.x;
  const int b = blockIdx.y;
  const int p0 = blockIdx.x * 32;
  const int wv = t >> 6;
  const int lane = t & 63;
  const int lr = lane & 15;
  const int lg = lane >> 4;

  {
    const float* qb = io + (size_t)b * 128 * NPIX + p0;
    const int r = t >> 3, c4 = (t & 7) * 4;
#pragma unroll
    for (int pass = 0; pass < 4; ++pass) {
      const int row = pass * 32 + r;
      const int dl = row & 31;
      const int pc = (row & ~31) | (((dl >> 2) & 3) * 8 + ((dl >> 4) & 1) * 4 + (dl & 3));
      const float4 v = *(const float4*)(qb + (size_t)row * NPIX + c4);
      qT[(c4 + 0) * 136 + pc] = f2bf(v.x);
      qT[(c4 + 1) * 136 + pc] = f2bf(v.y);
      qT[(c4 + 2) * 136 + pc] = f2bf(v.z);
      qT[(c4 + 3) * 136 + pc] = f2bf(v.w);
    }
  }
  __syncthreads();
  {
    f32x4 o1a[2][2];
#pragma unroll
    for (int i = 0; i < 2; ++i)
#pragma unroll
      for (int j = 0; j < 2; ++j)
#pragma unroll
        for (int q = 0; q < 4; ++q) o1a[i][j][q] = 0.f;
    const unsigned short* cbase = ctxnT + (size_t)(b * 4 + wv) * 1024;
#pragma unroll
    for (int mt = 0; mt < 2; ++mt) {
      const short8 af = *(const short8*)(cbase + (mt * 16 + lr) * 32 + lg * 8);
#pragma unroll
      for (int nt = 0; nt < 2; ++nt) {
        const short8 bf = *(const short8*)&qT[(nt * 16 + lr) * 136 + wv * 32 + lg * 8];
        o1a[mt][nt] = __builtin_amdgcn_mfma_f32_16x16x32_bf16(af, bf, o1a[mt][nt], 0, 0, 0);
      }
    }
#pragma unroll
    for (int mt = 0; mt < 2; ++mt)
#pragma unroll
      for (int nt = 0; nt < 2; ++nt)
#pragma unroll
        for (int q = 0; q < 4; ++q) {
          const int e = wv * 32 + mt * 16 + lg * 4 + q;
          o1T[(nt * 16 + lr) * 136 + e] = f2bf(o1a[mt][nt][q]);
        }
  }
  __syncthreads();
  f32x4 y[2][2];
#pragma unroll
  for (int i = 0; i < 2; ++i)
#pragma unroll
    for (int j = 0; j < 2; ++j)
#pragma unroll
      for (int q = 0; q < 4; ++q) y[i][j][q] = 0.f;
  const unsigned short* wbase = owb2 + (size_t)(wv * 8) * 512 + lane * 8;
#pragma unroll
  for (int mt = 0; mt < 2; ++mt) {
#pragma unroll
    for (int ks = 0; ks < 4; ++ks) {
      const short8 af = *(const short8*)(wbase + (size_t)(mt * 4 + ks) * 512);
#pragma unroll
      for (int nt = 0; nt < 2; ++nt) {
        const short8 bf = *(const short8*)&o1T[(nt * 16 + lr) * 136 + ks * 32 + lg * 8];
        y[mt][nt] = __builtin_amdgcn_mfma_f32_16x16x32_bf16(af, bf, y[mt][nt], 0, 0, 0);
      }
    }
  }
  {
    float ss[2] = {0.f, 0.f};
#pragma unroll
    for (int mt = 0; mt < 2; ++mt)
#pragma unroll
      for (int q = 0; q < 4; ++q) {
        const int row = 32 * wv + mt * 16 + lg * 4 + q;
        const float bb = out_b[row];
#pragma unroll
        for (int nt = 0; nt < 2; ++nt) {
          y[mt][nt][q] += bb;
          ss[nt] = fmaf(y[mt][nt][q], y[mt][nt][q], ss[nt]);
        }
      }
#pragma unroll
    for (int nt = 0; nt < 2; ++nt)
      redu[(wv * 4 + lg) * 32 + nt * 16 + lr] = ss[nt];
  }
  __syncthreads();
  if (t < 32) {
    float s = 0.f;
#pragma unroll
    for (int g = 0; g < 16; ++g) s += redu[g * 32 + t];
    inv[t] = SQRT128 / fmaxf(sqrtf(s), 1e-12f);
  }
  __syncthreads();
  {
    float* ob = io + (size_t)b * 128 * NPIX + p0;
#pragma unroll
    for (int mt = 0; mt < 2; ++mt)
#pragma unroll
      for (int q = 0; q < 4; ++q) {
        const int row = 32 * wv + mt * 16 + lg * 4 + q;
        const float g = out_norm_g[row];
#pragma unroll
        for (int nt = 0; nt < 2; ++nt) {
          const int col = nt * 16 + lr;
          ob[(size_t)row * NPIX + col] = y[mt][nt][q] * inv[col] * g;
        }
      }
  }
}

extern "C" void kernel_launch(void* const* d_in, const int* in_sizes, int n_in,
                              void* d_out, int out_size, void* d_ws, size_t ws_size,
                              hipStream_t stream) {
  const float* x          = (const float*)d_in[0];
  const float* norm_g     = (const float*)d_in[1];
  const float* qkv_w      = (const float*)d_in[2];
  const float* mem_kv     = (const float*)d_in[3];
  const float* out_w      = (const float*)d_in[4];
  const float* out_b      = (const float*)d_in[5];
  const float* out_norm_g = (const float*)d_in[6];
  float* out = (float*)d_out;

  const size_t PC = (size_t)16 * NBLK * 4096;   // f32 units
  const size_t PS = (size_t)16 * NBLK * 128;    // f32 units
  const size_t QB = (size_t)16 * NPIX * 128;    // u16 units
  const size_t need = (PC + PS) * 4 + (49152 + 16384 + 65536 + QB) * 2;

  if (ws_size >= need) {
    float* part_ctx = (float*)d_ws;
    float* part_se  = part_ctx + PC;
    unsigned short* wbf2  = (unsigned short*)(part_se + PS);
    unsigned short* owb2  = wbf2 + 49152;
    unsigned short* ctxnT = owb2 + 16384;
    unsigned short* qbf   = ctxnT + 65536;
    k_prep2<<<32, 256, 0, stream>>>(qkv_w, norm_g, out_w, wbf2, owb2);
    k1<true><<<dim3(NBLK, 16), 256, 0, stream>>>(x, wbf2, qbf, nullptr, part_ctx, part_se);
    k_reduce<<<256, 256, 0, stream>>>(part_ctx, part_se, mem_kv, ctxnT);
    k3_ws<<<dim3(NTILE, 16), 256, 0, stream>>>(ctxnT, owb2, qbf, out_b, out_norm_g, out);
  } else {
    float* ctxG = (float*)d_ws;                  // 65536 f32
    float* seG  = ctxG + 65536;                  // 2048 f32
    unsigned short* wbf2  = (unsigned short*)(seG + 2048);
    unsigned short* owb2  = wbf2 + 49152;
    unsigned short* ctxnT = owb2 + 16384;
    k_prep2<<<32, 256, 0, stream>>>(qkv_w, norm_g, out_w, wbf2, owb2);
    k_init<<<64, 256, 0, stream>>>(mem_kv, ctxG, seG);
    k1<false><<<dim3(NBLK, 16), 256, 0, stream>>>(x, wbf2, nullptr, out, ctxG, seG);
    k_norm<<<16, 256, 0, stream>>>(ctxG, seG, ctxnT);
    k3f<<<dim3(NTILE, 16), 256, 0, stream>>>(ctxnT, owb2, out_b, out_norm_g, out);
  }
}